// Round 3
// baseline (471.950 us; speedup 1.0000x reference)
//
#include <hip/hip_runtime.h>

// CRF classifier: emissions GEMM + forward (loss) + viterbi (+backtrace).
// Shapes fixed: B=64, T=512, H=768, L=32.
constexpr int Bn = 64, Tn = 512, Hn = 768, Ln = 32;

// ---------------- emissions = hs @ W + b  (f32, vector ALU) ----------------
// 256 blocks x 256 thr. Block = 128 rows; thread = 1 row x 32 cols x K-half(384).
// hs staged via LDS in 12 chunks of 32 k (coalesced, padded tile); W via
// wave-uniform scalar loads (SGPR operand in v_fma).
__global__ __launch_bounds__(256) void emis_gemm(const float* __restrict__ hs,
                                                 const float* __restrict__ W,
                                                 const float* __restrict__ bias,
                                                 float* __restrict__ em) {
  __shared__ __align__(16) float tile[2][128][33];   // 33.8 KB (pad -> conflict-free)
  const int tid = threadIdx.x;
  const int hf = tid >> 7;                 // K half (wave-uniform)
  const int hfu = __builtin_amdgcn_readfirstlane(hf);  // provably uniform for s_load
  const int row = tid & 127;
  const long row0 = (long)blockIdx.x * 128;

  float4 ld[8];
  int lc4[8], lr[8], lh2[8];
#pragma unroll
  for (int p = 0; p < 8; ++p) {            // fidx bijection: c4(3b) r(7b) h2(1b)
    int fidx = p * 256 + tid;
    lc4[p] = fidx & 7; lr[p] = (fidx >> 3) & 127; lh2[p] = fidx >> 10;
  }

  float acc[32];
#pragma unroll
  for (int c = 0; c < 32; ++c) acc[c] = 0.f;

#pragma unroll
  for (int p = 0; p < 8; ++p)              // prologue: chunk 0 -> regs
    ld[p] = *(const float4*)(hs + (row0 + lr[p]) * Hn + lh2[p] * 384 + lc4[p] * 4);

  for (int ch = 0; ch < 12; ++ch) {
    __syncthreads();
#pragma unroll
    for (int p = 0; p < 8; ++p)
      *(float4*)&tile[lh2[p]][lr[p]][lc4[p] * 4] = ld[p];
    __syncthreads();
    if (ch < 11) {
#pragma unroll
      for (int p = 0; p < 8; ++p)          // prefetch next chunk while computing
        ld[p] = *(const float4*)(hs + (row0 + lr[p]) * Hn + lh2[p] * 384 +
                                 (ch + 1) * 32 + lc4[p] * 4);
    }
    const float* tp = &tile[hf][row][0];
    const float* wb_ = W + (hfu * 384 + ch * 32) * Ln;   // uniform base -> s_load
#pragma unroll 4
    for (int kk = 0; kk < 32; ++kk) {
      float h = tp[kk];
      const float* wr = wb_ + kk * Ln;
#pragma unroll
      for (int c = 0; c < 32; ++c) acc[c] = fmaf(h, wr[c], acc[c]);
    }
  }
  // combine halves + bias (same summation order as before: (acc0 + acc1) + b)
  __syncthreads();
  float* cb = &tile[0][0][0];              // reuse as [128][36] (16B-aligned rows)
  if (hf == 1) {
#pragma unroll
    for (int c = 0; c < 32; ++c) cb[row * 36 + c] = acc[c];
  }
  __syncthreads();
  if (hf == 0) {
#pragma unroll
    for (int c4 = 0; c4 < 8; ++c4) {
      float4 p = *(float4*)&cb[row * 36 + c4 * 4];
      float4 bv = ((const float4*)bias)[c4];
      float4 o = make_float4((acc[c4 * 4 + 0] + p.x) + bv.x,
                             (acc[c4 * 4 + 1] + p.y) + bv.y,
                             (acc[c4 * 4 + 2] + p.z) + bv.z,
                             (acc[c4 * 4 + 3] + p.w) + bv.w);
      *(float4*)&em[(row0 + row) * Ln + c4 * 4] = o;
    }
  }
}

// ---------------- forward + viterbi scans + backtrace ----------------
// 32 blocks x 128 threads: wave 0 = viterbi (2 batches via halves),
// wave 1 = forward (same 2 batches). 2 waves/CU -> LDS pipe uncontended.
__global__ __launch_bounds__(128) void crf_scan(const float* __restrict__ em,
                                                const int* __restrict__ mask,
                                                const int* __restrict__ labels,
                                                const float* __restrict__ startT,
                                                const float* __restrict__ endT,
                                                const float* __restrict__ trans,
                                                float* __restrict__ outp) {
  __shared__ unsigned char hist[2][Tn][Ln];        // 32 KB backpointers (u8)
  __shared__ __align__(16) float stage[2][64];     // per-wave broadcast buffers
  __shared__ unsigned char Ctab[2][32][32];        // chunk-composition tables
  __shared__ int bnd[2][33];
  __shared__ int bl_lds[2];
  __shared__ int len_lds[2];

  const int tid = threadIdx.x;
  const int wid = tid >> 6;                        // 0 = viterbi, 1 = forward
  const int lane = tid & 63;
  const int half = lane >> 5;
  const int j = lane & 31;
  const int batch = blockIdx.x * 2 + half;

  // sequence length of this lane's batch (mask monotone)
  int s = 0;
  for (int t = j; t < Tn; t += 32) s += mask[batch * Tn + t];
#pragma unroll
  for (int m = 1; m <= 16; m <<= 1) s += __shfl_xor(s, m);
  const int len = s;                               // in [256, 512]
  const int lw = max(len, __shfl_xor(len, 32));    // wave loop bound
  const float* emb = em + (long)batch * Tn * Ln;

  if (wid == 0) {
    // ---------------- viterbi ----------------
    if (j == 0) len_lds[half] = len;
    float tr[32];
#pragma unroll
    for (int i = 0; i < 32; ++i) tr[i] = trans[i * Ln + j];
    float score = startT[j] + emb[j];
    float emn = emb[Ln + j];
    for (int t = 1; t < lw; ++t) {
      float em_t = emn;
      int tn = t + 1 < Tn ? t + 1 : Tn - 1;
      emn = emb[tn * Ln + j];
      stage[wid][lane] = score;                    // same-wave LDS broadcast
      const float* sb = &stage[wid][half * 32];
      float v[32];
#pragma unroll
      for (int q4 = 0; q4 < 8; ++q4) {
        float4 s4 = *(const float4*)(sb + q4 * 4);
        v[q4 * 4 + 0] = s4.x + tr[q4 * 4 + 0];
        v[q4 * 4 + 1] = s4.y + tr[q4 * 4 + 1];
        v[q4 * 4 + 2] = s4.z + tr[q4 * 4 + 2];
        v[q4 * 4 + 3] = s4.w + tr[q4 * 4 + 3];
      }
      // exact max via tree (fuses to v_max3); argmax off critical path
      float w[16];
#pragma unroll
      for (int q = 0; q < 16; ++q) w[q] = fmaxf(v[q], v[q + 16]);
#pragma unroll
      for (int sz = 8; sz >= 1; sz >>= 1)
#pragma unroll
        for (int q = 0; q < sz; ++q) w[q] = fmaxf(w[q], w[q + sz]);
      const float mv = w[0];
      int mi = 31;
#pragma unroll
      for (int i = 31; i >= 0; --i) mi = (v[i] == mv) ? i : mi;  // first max
      hist[half][t - 1][j] = (unsigned char)mi;
      score = (t < len) ? (mv + em_t) : score;
    }
    // identity-patch rows [len-1, 511]
    for (int x = j; x < (Tn + 1 - len) * Ln; x += 32) {
      int rr = len - 1 + (x >> 5);
      hist[half][rr][x & 31] = (unsigned char)(x & 31);
    }
    // best_last: first-index argmax of (score + end)
    float bv = score + endT[j];
    int bj = j;
#pragma unroll
    for (int m = 1; m <= 16; m <<= 1) {
      float ov = __shfl_xor(bv, m);
      int oi = __shfl_xor(bj, m);
      if (ov > bv || (ov == bv && oi < bj)) { bv = ov; bj = oi; }
    }
    if (j == 0) bl_lds[half] = bj;
  } else {
    // ---------------- forward (log-domain, shift by batch lane-0 score) -----
    float et[32];
#pragma unroll
    for (int i = 0; i < 32; ++i) et[i] = __expf(trans[i * Ln + j]);
    float score = startT[j] + emb[j];
    float emn = emb[Ln + j];
    for (int t = 1; t < lw; ++t) {
      float em_t = emn;
      int tn = t + 1 < Tn ? t + 1 : Tn - 1;
      emn = emb[tn * Ln + j];
      float s0 = __shfl(score, lane & 32);         // per-batch uniform shift
      float e = __expf(score - s0);
      stage[wid][lane] = e;
      const float* eb = &stage[wid][half * 32];
      float a0 = 0.f, a1 = 0.f, a2 = 0.f, a3 = 0.f;
#pragma unroll
      for (int q = 0; q < 8; ++q) {
        float4 ev = *(const float4*)(eb + q * 4);
        a0 = fmaf(ev.x, et[q * 4 + 0], a0);
        a1 = fmaf(ev.y, et[q * 4 + 1], a1);
        a2 = fmaf(ev.z, et[q * 4 + 2], a2);
        a3 = fmaf(ev.w, et[q * 4 + 3], a3);
      }
      float nx = s0 + __logf((a0 + a1) + (a2 + a3)) + em_t;
      score = (t < len) ? nx : score;
    }
    // denom = LSE_j(score + end), within 32-lane half
    float v = score + endT[j];
    float mx = v;
#pragma unroll
    for (int m = 1; m <= 16; m <<= 1) mx = fmaxf(mx, __shfl_xor(mx, m));
    float ssum = __expf(v - mx);
#pragma unroll
    for (int m = 1; m <= 16; m <<= 1) ssum += __shfl_xor(ssum, m);
    float denom = mx + __logf(ssum);
    // numer (gold-path score), strided over the half's 32 lanes
    float part = 0.f;
    const int* lab = labels + batch * Tn;
    for (int t = j; t < Tn; t += 32) {
      int lt = lab[t];
      if (t == 0)
        part += startT[lt] + emb[lt];
      else if (t < len)
        part += emb[t * Ln + lt] + trans[lab[t - 1] * Ln + lt];
    }
#pragma unroll
    for (int m = 1; m <= 16; m <<= 1) part += __shfl_xor(part, m);
    if (j == 0) {
      int lastl = lab[len - 1];
      atomicAdd(outp, denom - (part + endT[lastl]));  // loss contribution
    }
  }
  __syncthreads();

  // ---------------- parallel backtrace: wave wid -> local batch wid ----------
  {
    const int wb2 = wid;
    const int batch2 = blockIdx.x * 2 + wb2;
    const int len2 = len_lds[wb2];
    const int best_last = bl_lds[wb2];
    const int kh2 = lane >> 5;
    // phase 1: compose 32 chunks of 16 backpointer maps
    int F[16];
#pragma unroll
    for (int kk = 0; kk < 16; ++kk) F[kk] = hist[wb2][16 * (kh2 * 16 + kk) + 15][j];
    for (int s2 = 14; s2 >= 0; --s2) {
#pragma unroll
      for (int kk = 0; kk < 16; ++kk) F[kk] = hist[wb2][16 * (kh2 * 16 + kk) + s2][F[kk]];
    }
#pragma unroll
    for (int kk = 0; kk < 16; ++kk) Ctab[wb2][kh2 * 16 + kk][j] = (unsigned char)F[kk];
    __syncthreads();
    // phase 2: boundary carries (sequential, lane 0 of each wave)
    if (lane == 0) {
      int c = best_last;
      bnd[wb2][32] = c;
      for (int k = 31; k >= 0; --k) {
        c = Ctab[wb2][k][c];
        bnd[wb2][k] = c;
      }
    }
    __syncthreads();
    // phase 3: 32 lanes replay their chunk, write predictions
    if (lane < 32) {
      int c = bnd[wb2][lane + 1];
      float* po = outp + 1 + (long)batch2 * Tn;
#pragma unroll
      for (int s3 = 15; s3 >= 0; --s3) {
        int t = 16 * lane + s3;
        c = hist[wb2][t][c];
        po[t] = (t < len2) ? (float)c : 0.0f;      // PAD = 0 beyond last_idx
      }
    }
  }
}

extern "C" void kernel_launch(void* const* d_in, const int* in_sizes, int n_in,
                              void* d_out, int out_size, void* d_ws, size_t ws_size,
                              hipStream_t stream) {
  const float* hs = (const float*)d_in[0];      // (64,512,768) f32
  const int* mask = (const int*)d_in[1];        // (64,512) i32
  const int* labels = (const int*)d_in[2];      // (64,512) i32
  const float* W = (const float*)d_in[3];       // (768,32) f32
  const float* b = (const float*)d_in[4];       // (32,) f32
  const float* startT = (const float*)d_in[5];  // (32,)
  const float* endT = (const float*)d_in[6];    // (32,)
  const float* trans = (const float*)d_in[7];   // (32,32)
  float* out = (float*)d_out;                   // [loss, pred_labels(64*512)] f32
  float* em = (float*)d_ws;                     // 4 MB emissions

  emis_gemm<<<256, 256, 0, stream>>>(hs, W, b, em);
  hipMemsetAsync(d_out, 0, sizeof(float), stream);  // zero loss accumulator
  crf_scan<<<32, 128, 0, stream>>>(em, mask, labels, startT, endT, trans, out);
}